// Round 1
// baseline (48098.401 us; speedup 1.0000x reference)
//
#include <hip/hip_runtime.h>
#include <math.h>

#define Bn   128
#define Sn   336
#define INd  64
#define Hn   1024
#define Tn   96
#define G4   4096    // 4*H
#define KENC 1088    // INd + Hn   (34 chunks of 32)
#define KDEC 2080    // 1 + Hn + Hn = 2049, padded to 65*32
#define KQ   1024

__device__ __forceinline__ float sigmoidf_(float x){ return 1.0f/(1.0f+expf(-x)); }

// ---------------- weight packing: gate-interleaved rows --------------------
// packed row r: unit u = r>>2, gate g = r&3 (i,f,g,o), orig row = g*Hn + u
__global__ void pack_enc(const float* __restrict__ Wih, const float* __restrict__ Whh,
                         const float* __restrict__ bih, const float* __restrict__ bhh,
                         float* __restrict__ Wcat, float* __restrict__ bcat){
    int n = G4*KENC;
    for (int idx = blockIdx.x*256 + threadIdx.x; idx < n; idx += gridDim.x*256){
        int r = idx / KENC, k = idx % KENC;
        int u = r >> 2, g = r & 3;
        int orig = g*Hn + u;
        Wcat[idx] = (k < INd) ? Wih[orig*INd + k] : Whh[orig*Hn + (k - INd)];
    }
    int tid = blockIdx.x*256 + threadIdx.x;
    if (tid < G4){
        int u = tid >> 2, g = tid & 3; int orig = g*Hn + u;
        bcat[tid] = bih[orig] + bhh[orig];
    }
}

__global__ void pack_dec(const float* __restrict__ Wih, const float* __restrict__ Whh,
                         const float* __restrict__ bih, const float* __restrict__ bhh,
                         float* __restrict__ Wcat, float* __restrict__ bcat){
    long n = (long)G4*KDEC;
    for (long idx = (long)blockIdx.x*256 + threadIdx.x; idx < n; idx += (long)gridDim.x*256){
        int r = (int)(idx / KDEC), k = (int)(idx % KDEC);
        int u = r >> 2, g = r & 3;
        int orig = g*Hn + u;
        float v;
        if (k <= Hn)            v = Wih[orig*(Hn+1) + k];       // k=0: prev_y col; 1..1024: ctx cols
        else if (k <= 2*Hn)     v = Whh[orig*Hn + (k - 1 - Hn)];
        else                    v = 0.0f;                        // pad 2049..2079
        Wcat[idx] = v;
    }
    int tid = blockIdx.x*256 + threadIdx.x;
    if (tid < G4){
        int u = tid >> 2, g = tid & 3; int orig = g*Hn + u;
        bcat[tid] = bih[orig] + bhh[orig];
    }
}

__global__ void init_state(float* __restrict__ h0, float* __restrict__ c, float* __restrict__ pv){
    int idx = blockIdx.x*256 + threadIdx.x;
    if (idx < Bn*Hn){ h0[idx] = 0.0f; c[idx] = 0.0f; }
    if (idx < Bn) pv[idx] = 0.0f;
}

// ---------------- fused step GEMM + LSTM epilogue --------------------------
// C[M=128, N] = A[M,K] @ W[N,K]^T ; MODE 0=enc LSTM, 1=dec LSTM, 2=attn query
// tile 32(M) x 64(N), 256 threads, each thread: 2 rows x 4 cols (one unit's 4 gates)
template<int MODE, int K>
__global__ __launch_bounds__(256)
void step_gemm(const float* __restrict__ h_in,
               const float* __restrict__ src,
               const float* __restrict__ ctx,
               const float* __restrict__ prevy,
               const float* __restrict__ W,      // [N][K] row-major
               const float* __restrict__ bcat,
               float* __restrict__ c,
               float* __restrict__ outp,         // h_out (LSTM) or q (MODE 2)
               float* __restrict__ enc_out,
               int t){
    __shared__ float As[32][33];
    __shared__ float Bs[64][33];
    int tid = threadIdx.x;
    int bm0 = blockIdx.x * 32;
    int bn0 = blockIdx.y * 64;
    int cg = tid & 15;        // column group: 4 cols = 1 unit
    int rg = tid >> 4;        // 0..15
    int r0 = rg * 2;

    float acc[2][4] = {{0,0,0,0},{0,0,0,0}};

    for (int k0 = 0; k0 < K; k0 += 32){
        #pragma unroll
        for (int i = 0; i < 4; i++){
            int e = tid + i*256;
            int row = e >> 5, kk = e & 31;
            int b = bm0 + row, k = k0 + kk;
            float v;
            if (MODE == 0)      v = (k < INd) ? src[(b*Sn + t)*INd + k] : h_in[b*Hn + (k - INd)];
            else if (MODE == 1) v = (k == 0) ? prevy[b]
                                  : (k <= Hn)   ? ctx [b*Hn + (k - 1)]
                                  : (k <= 2*Hn) ? h_in[b*Hn + (k - 1 - Hn)]
                                  : 0.0f;
            else                v = h_in[b*Hn + k];
            As[row][kk] = v;
        }
        #pragma unroll
        for (int i = 0; i < 8; i++){
            int e = tid + i*256;
            int col = e >> 5, kk = e & 31;
            Bs[col][kk] = W[(long)(bn0 + col)*K + k0 + kk];
        }
        __syncthreads();
        #pragma unroll
        for (int kk = 0; kk < 32; kk++){
            float a0 = As[r0][kk], a1 = As[r0+1][kk];
            float w0 = Bs[cg*4+0][kk], w1 = Bs[cg*4+1][kk];
            float w2 = Bs[cg*4+2][kk], w3 = Bs[cg*4+3][kk];
            acc[0][0] += a0*w0; acc[0][1] += a0*w1; acc[0][2] += a0*w2; acc[0][3] += a0*w3;
            acc[1][0] += a1*w0; acc[1][1] += a1*w1; acc[1][2] += a1*w2; acc[1][3] += a1*w3;
        }
        __syncthreads();
    }

    if (MODE == 2){
        #pragma unroll
        for (int r = 0; r < 2; r++){
            int b = bm0 + r0 + r;
            #pragma unroll
            for (int j = 0; j < 4; j++) outp[b*Hn + bn0 + cg*4 + j] = acc[r][j];
        }
    } else {
        int u = (bn0 >> 2) + cg;
        int colb = bn0 + cg*4;
        float bi = bcat[colb+0], bf = bcat[colb+1], bg = bcat[colb+2], bo = bcat[colb+3];
        #pragma unroll
        for (int r = 0; r < 2; r++){
            int b = bm0 + r0 + r;
            float gi = acc[r][0] + bi;
            float gf = acc[r][1] + bf;
            float gg = acc[r][2] + bg;
            float go = acc[r][3] + bo;
            float c_old = c[b*Hn + u];
            float c_new = sigmoidf_(gf)*c_old + sigmoidf_(gi)*tanhf(gg);
            float hv = sigmoidf_(go)*tanhf(c_new);
            c[b*Hn + u] = c_new;
            outp[b*Hn + u] = hv;
            if (MODE == 0) enc_out[((long)b*Sn + t)*Hn + u] = hv;
        }
    }
}

// ---------------- attention: energies ---------------------------------------
__global__ __launch_bounds__(256)
void energy_kernel(const float* __restrict__ q, const float* __restrict__ enc,
                   float* __restrict__ energy){
    int b = blockIdx.x;
    int wave = threadIdx.x >> 6, lane = threadIdx.x & 63;
    int s = blockIdx.y*4 + wave;
    const float4* qp = (const float4*)(q + b*Hn);
    const float4* ep = (const float4*)(enc + ((long)b*Sn + s)*Hn);
    float acc = 0.0f;
    #pragma unroll
    for (int i = 0; i < 4; i++){
        float4 qv = qp[lane + i*64];
        float4 ev = ep[lane + i*64];
        acc += qv.x*ev.x + qv.y*ev.y + qv.z*ev.z + qv.w*ev.w;
    }
    #pragma unroll
    for (int off = 32; off; off >>= 1) acc += __shfl_down(acc, off);
    if (lane == 0) energy[b*Sn + s] = acc;
}

// ---------------- attention: softmax + context ------------------------------
__global__ __launch_bounds__(256)
void softmax_ctx_kernel(const float* __restrict__ energy, const float* __restrict__ enc,
                        float* __restrict__ ctx){
    __shared__ float w[Sn];
    __shared__ float red[256];
    int b = blockIdx.x, tid = threadIdx.x;
    float m = -1e30f;
    for (int s = tid; s < Sn; s += 256){ float e = energy[b*Sn + s]; w[s] = e; m = fmaxf(m, e); }
    red[tid] = m; __syncthreads();
    for (int o = 128; o; o >>= 1){ if (tid < o) red[tid] = fmaxf(red[tid], red[tid+o]); __syncthreads(); }
    m = red[0]; __syncthreads();
    float sum = 0.0f;
    for (int s = tid; s < Sn; s += 256){ float e = expf(w[s] - m); w[s] = e; sum += e; }
    red[tid] = sum; __syncthreads();
    for (int o = 128; o; o >>= 1){ if (tid < o) red[tid] += red[tid+o]; __syncthreads(); }
    float inv = 1.0f / red[0];
    float acc[4] = {0,0,0,0};
    for (int s = 0; s < Sn; s++){
        float ws = w[s] * inv;
        const float* ep = enc + ((long)b*Sn + s)*Hn;
        #pragma unroll
        for (int j = 0; j < 4; j++) acc[j] += ws * ep[tid + j*256];
    }
    #pragma unroll
    for (int j = 0; j < 4; j++) ctx[b*Hn + tid + j*256] = acc[j];
}

// ---------------- fc head + feedback ---------------------------------------
__global__ __launch_bounds__(256)
void fc_out_kernel(const float* __restrict__ h, const float* __restrict__ fcW,
                   const float* __restrict__ fcb, float* __restrict__ out,
                   float* __restrict__ prevy, int t){
    __shared__ float red[256];
    int b = blockIdx.x, tid = threadIdx.x;
    float acc = 0.0f;
    #pragma unroll
    for (int j = 0; j < 4; j++) acc += h[b*Hn + tid + j*256] * fcW[tid + j*256];
    red[tid] = acc; __syncthreads();
    for (int o = 128; o; o >>= 1){ if (tid < o) red[tid] += red[tid+o]; __syncthreads(); }
    if (tid == 0){
        float p = red[0] + fcb[0];
        out[b*Tn + t] = p;
        prevy[b] = p;
    }
}

extern "C" void kernel_launch(void* const* d_in, const int* in_sizes, int n_in,
                              void* d_out, int out_size, void* d_ws, size_t ws_size,
                              hipStream_t stream){
    const float* src  = (const float*)d_in[0];
    const float* eWih = (const float*)d_in[1];
    const float* eWhh = (const float*)d_in[2];
    const float* ebih = (const float*)d_in[3];
    const float* ebhh = (const float*)d_in[4];
    const float* dWih = (const float*)d_in[5];
    const float* dWhh = (const float*)d_in[6];
    const float* dbih = (const float*)d_in[7];
    const float* dbhh = (const float*)d_in[8];
    const float* attnW= (const float*)d_in[9];
    const float* fcW  = (const float*)d_in[10];
    const float* fcb  = (const float*)d_in[11];
    float* out = (float*)d_out;

    float* ws = (float*)d_ws;
    size_t off = 0;
    float* Wenc = ws + off;  off += (size_t)G4*KENC;
    float* benc = ws + off;  off += G4;
    float* Wdec = ws + off;  off += (size_t)G4*KDEC;
    float* bdec = ws + off;  off += G4;
    float* h0   = ws + off;  off += (size_t)Bn*Hn;
    float* h1   = ws + off;  off += (size_t)Bn*Hn;
    float* cbuf = ws + off;  off += (size_t)Bn*Hn;
    float* enco = ws + off;  off += (size_t)Bn*Sn*Hn;
    float* q    = ws + off;  off += (size_t)Bn*Hn;
    float* ctx  = ws + off;  off += (size_t)Bn*Hn;
    float* ener = ws + off;  off += (size_t)Bn*Sn;
    float* pv   = ws + off;  off += Bn;

    pack_enc<<<4096, 256, 0, stream>>>(eWih, eWhh, ebih, ebhh, Wenc, benc);
    pack_dec<<<8192, 256, 0, stream>>>(dWih, dWhh, dbih, dbhh, Wdec, bdec);
    init_state<<<512, 256, 0, stream>>>(h0, cbuf, pv);

    float* hb[2] = {h0, h1};
    dim3 blk(256);
    dim3 gl(4, 64);   // LSTM GEMMs: 128/32 x 4096/64
    dim3 gq(4, 16);   // attn query: 128/32 x 1024/64

    for (int t = 0; t < Sn; t++){
        step_gemm<0, KENC><<<gl, blk, 0, stream>>>(hb[t&1], src, nullptr, nullptr,
                                                   Wenc, benc, cbuf, hb[(t+1)&1], enco, t);
    }
    for (int d = 0; d < Tn; d++){
        float* hc = hb[d&1];
        float* hn = hb[(d+1)&1];
        step_gemm<2, KQ><<<gq, blk, 0, stream>>>(hc, nullptr, nullptr, nullptr,
                                                 attnW, nullptr, nullptr, q, nullptr, 0);
        energy_kernel<<<dim3(Bn, 84), blk, 0, stream>>>(q, enco, ener);
        softmax_ctx_kernel<<<Bn, blk, 0, stream>>>(ener, enco, ctx);
        step_gemm<1, KDEC><<<gl, blk, 0, stream>>>(hc, nullptr, ctx, pv,
                                                   Wdec, bdec, cbuf, hn, nullptr, 0);
        fc_out_kernel<<<Bn, blk, 0, stream>>>(hn, fcW, fcb, out, pv, d);
    }
}

// Round 2
// 14260.428 us; speedup vs baseline: 3.3729x; 3.3729x over previous
//
#include <hip/hip_runtime.h>
#include <math.h>

#define Bn   128
#define Sn   336
#define INd  64
#define Hn   1024
#define Tn   96
#define G4   4096
#define KENC 1088   // 64 + 1024 = 34*32
#define KDEC 2080   // 1 + 1024 + 1024 + 31 pad = 65*32
#define KQ   1024

typedef __attribute__((ext_vector_type(8))) short short8;
typedef __attribute__((ext_vector_type(4))) float floatx4;

__device__ __forceinline__ float sigmoidf_(float x){ return 1.0f/(1.0f+expf(-x)); }

__device__ __forceinline__ unsigned short f2bf(float f){
    union { float f; unsigned u; } v; v.f = f;
    unsigned r = v.u + 0x7fffu + ((v.u >> 16) & 1u);
    return (unsigned short)(r >> 16);
}
__device__ __forceinline__ float bflo(unsigned u){ union{unsigned u; float f;} v; v.u = u << 16;        return v.f; }
__device__ __forceinline__ float bfhi(unsigned u){ union{unsigned u; float f;} v; v.u = u & 0xffff0000u; return v.f; }

__device__ __forceinline__ void gload16(const void* g, void* l){
    __builtin_amdgcn_global_load_lds((const __attribute__((address_space(1))) void*)g,
                                     (__attribute__((address_space(3))) void*)l, 16, 0, 0);
}

// ---------------- packing -------------------------------------------------
// packed row p: group = p>>6, gate g = (p>>4)&3, t = p&15, unit u = (p>>6)*16 + t
// orig row = g*Hn + u.  Gate-swizzle so a 64-wide n-group = 4 gates x 16 units.
__global__ void pack_enc(const float* __restrict__ Wih, const float* __restrict__ Whh,
                         const float* __restrict__ bih, const float* __restrict__ bhh,
                         unsigned short* __restrict__ Wp, float* __restrict__ bcat){
    int n = G4*KENC;
    for (int idx = blockIdx.x*256 + threadIdx.x; idx < n; idx += gridDim.x*256){
        int p = idx / KENC, k = idx % KENC;
        int g = (p >> 4) & 3, u = (p >> 6)*16 + (p & 15);
        int orig = g*Hn + u;
        float v = (k < INd) ? Wih[orig*INd + k] : Whh[(size_t)orig*Hn + k - INd];
        Wp[idx] = f2bf(v);
    }
    int tid = blockIdx.x*256 + threadIdx.x;
    if (tid < G4){
        int g = (tid >> 4) & 3, u = (tid >> 6)*16 + (tid & 15);
        int orig = g*Hn + u;
        bcat[tid] = bih[orig] + bhh[orig];
    }
}

__global__ void pack_dec(const float* __restrict__ Wih, const float* __restrict__ Whh,
                         const float* __restrict__ bih, const float* __restrict__ bhh,
                         unsigned short* __restrict__ Wp, float* __restrict__ bcat){
    long n = (long)G4*KDEC;
    for (long idx = (long)blockIdx.x*256 + threadIdx.x; idx < n; idx += (long)gridDim.x*256){
        int p = (int)(idx / KDEC), k = (int)(idx % KDEC);
        int g = (p >> 4) & 3, u = (p >> 6)*16 + (p & 15);
        int orig = g*Hn + u;
        float v;
        if (k <= Hn)        v = Wih[(size_t)orig*(Hn+1) + k];      // k=0 prev_y, 1..1024 ctx
        else if (k <= 2*Hn) v = Whh[(size_t)orig*Hn + (k - 1 - Hn)];
        else                v = 0.0f;
        Wp[idx] = f2bf(v);
    }
    int tid = blockIdx.x*256 + threadIdx.x;
    if (tid < G4){
        int g = (tid >> 4) & 3, u = (tid >> 6)*16 + (tid & 15);
        int orig = g*Hn + u;
        bcat[tid] = bih[orig] + bhh[orig];
    }
}

__global__ void pack_attn(const float* __restrict__ w, unsigned short* __restrict__ d){
    int n = Hn*Hn;
    for (int i = blockIdx.x*256 + threadIdx.x; i < n; i += gridDim.x*256) d[i] = f2bf(w[i]);
}

__global__ void conv_src(const float* __restrict__ s, unsigned short* __restrict__ d){
    int n = Bn*Sn*INd;
    for (int i = blockIdx.x*256 + threadIdx.x; i < n; i += gridDim.x*256) d[i] = f2bf(s[i]);
}

__global__ void init_ws(unsigned short* __restrict__ hb0, float* __restrict__ cbuf,
                        unsigned short* __restrict__ A0, unsigned short* __restrict__ A1){
    int i = blockIdx.x*256 + threadIdx.x;
    if (i < Bn*Hn){ hb0[i] = 0; cbuf[i] = 0.0f; }
    if (i < Bn*KDEC){ A0[i] = 0; A1[i] = 0; }
}

// ---------------- MFMA step GEMM + LSTM epilogue --------------------------
// C[128, 64-n-group] = A[128,K] @ W[ngroup][K]^T, bf16 in / fp32 acc.
// grid (2, N/64), 256 thr = 4 waves, wave w: rows m0+w*16..+15, all 64 n.
// n-subtile j = gate j (LSTM modes) per the gate-swizzled packing.
template<int MODE, int K>   // 0=enc LSTM, 1=dec LSTM, 2=attn query
__global__ __launch_bounds__(256)
void mfma_gemm(const unsigned short* __restrict__ Abase,
               const unsigned short* __restrict__ srcbf,
               const unsigned short* __restrict__ W,
               const float* __restrict__ bcat,
               float* __restrict__ cst,
               unsigned short* __restrict__ hout,
               unsigned short* __restrict__ adec_h,   // next Adec + 1025
               unsigned short* __restrict__ encout,
               int t)
{
    __shared__ __align__(16) unsigned short As[64*32];
    __shared__ __align__(16) unsigned short Bs[64*32];
    const int tid = threadIdx.x;
    const int l = tid & 63;
    const int w = tid >> 6;
    const int m0 = blockIdx.x * 64;
    const int n0 = blockIdx.y * 64;

    floatx4 acc0 = {0,0,0,0}, acc1 = {0,0,0,0}, acc2 = {0,0,0,0}, acc3 = {0,0,0,0};

    // staging: thread e loads 16B chunk; row = e>>2, k-chunk = (e&3)*8
    const int arow = tid >> 2;
    const int kch  = (tid & 3) << 3;
    const int am   = m0 + arow;
    const unsigned short* wptr = W + (size_t)(n0 + arow) * K + kch;
    const unsigned short* aptr;
    if (MODE == 0)      aptr = Abase + (size_t)am * Hn + kch - INd;  // deref only when k0>=64
    else if (MODE == 1) aptr = Abase + (size_t)am * KDEC + kch;
    else                aptr = Abase + (size_t)am * Hn + kch;
    const unsigned short* srcrow = (MODE == 0) ? srcbf + ((size_t)am * Sn + t) * INd + kch : nullptr;

    void* ldsA = (void*)((char*)As + w * 1024);
    void* ldsB = (void*)((char*)Bs + w * 1024);

    const int aoff  = (w*16 + (l & 15)) * 64 + (l >> 4) * 16;  // bytes
    const int boff  = (l & 15) * 64 + (l >> 4) * 16;

    for (int k0 = 0; k0 < K; k0 += 32){
        const unsigned short* ga;
        if (MODE == 0) ga = (k0 < INd) ? (srcrow + k0) : (aptr + k0);
        else           ga = aptr + k0;
        gload16(ga, ldsA);
        gload16(wptr + k0, ldsB);
        __syncthreads();
        short8 a  = *(const short8*)((const char*)As + aoff);
        short8 b0 = *(const short8*)((const char*)Bs + boff);
        short8 b1 = *(const short8*)((const char*)Bs + boff + 16*64);
        short8 b2 = *(const short8*)((const char*)Bs + boff + 32*64);
        short8 b3 = *(const short8*)((const char*)Bs + boff + 48*64);
        acc0 = __builtin_amdgcn_mfma_f32_16x16x32_bf16(a, b0, acc0, 0, 0, 0);
        acc1 = __builtin_amdgcn_mfma_f32_16x16x32_bf16(a, b1, acc1, 0, 0, 0);
        acc2 = __builtin_amdgcn_mfma_f32_16x16x32_bf16(a, b2, acc2, 0, 0, 0);
        acc3 = __builtin_amdgcn_mfma_f32_16x16x32_bf16(a, b3, acc3, 0, 0, 0);
        __syncthreads();
    }

    const int rbase = m0 + w*16 + ((l >> 4) << 2);   // C/D: row = quad*4 + reg
    const int col = l & 15;
    if (MODE == 2){
        #pragma unroll
        for (int r = 0; r < 4; r++){
            unsigned short* qp = hout + (size_t)(rbase + r) * Hn + n0 + col;
            qp[0]  = f2bf(acc0[r]);
            qp[16] = f2bf(acc1[r]);
            qp[32] = f2bf(acc2[r]);
            qp[48] = f2bf(acc3[r]);
        }
    } else {
        const int u = blockIdx.y * 16 + col;
        const float bi  = bcat[n0 + col];
        const float bf_ = bcat[n0 + 16 + col];
        const float bg  = bcat[n0 + 32 + col];
        const float bo  = bcat[n0 + 48 + col];
        #pragma unroll
        for (int r = 0; r < 4; r++){
            const int m = rbase + r;
            float gi = acc0[r] + bi;
            float gf = acc1[r] + bf_;
            float gg = acc2[r] + bg;
            float go = acc3[r] + bo;
            float co = cst[(size_t)m * Hn + u];
            float cn = sigmoidf_(gf) * co + sigmoidf_(gi) * tanhf(gg);
            float hv = sigmoidf_(go) * tanhf(cn);
            cst[(size_t)m * Hn + u] = cn;
            unsigned short hb = f2bf(hv);
            hout[(size_t)m * Hn + u] = hb;
            adec_h[(size_t)m * KDEC + u] = hb;
            if (MODE == 0) encout[((size_t)m * Sn + t) * Hn + u] = hb;
        }
    }
}

// ---------------- attention: energies (bf16 dot) ---------------------------
__global__ __launch_bounds__(256)
void energy_kernel(const unsigned short* __restrict__ q, const unsigned short* __restrict__ enc,
                   float* __restrict__ energy){
    int b = blockIdx.x;
    int wv = threadIdx.x >> 6, l = threadIdx.x & 63;
    int s = blockIdx.y*4 + wv;
    const uint4* qp = (const uint4*)(q + (size_t)b*Hn);
    const uint4* ep = (const uint4*)(enc + ((size_t)b*Sn + s)*Hn);
    float acc = 0.0f;
    #pragma unroll
    for (int i = 0; i < 2; i++){
        uint4 qv = qp[l + i*64];
        uint4 ev = ep[l + i*64];
        acc += bflo(qv.x)*bflo(ev.x) + bfhi(qv.x)*bfhi(ev.x);
        acc += bflo(qv.y)*bflo(ev.y) + bfhi(qv.y)*bfhi(ev.y);
        acc += bflo(qv.z)*bflo(ev.z) + bfhi(qv.z)*bfhi(ev.z);
        acc += bflo(qv.w)*bflo(ev.w) + bfhi(qv.w)*bfhi(ev.w);
    }
    #pragma unroll
    for (int off = 32; off; off >>= 1) acc += __shfl_down(acc, off);
    if (l == 0) energy[b*Sn + s] = acc;
}

// ---------------- attention: softmax + context (writes ctx into Adec) ------
__global__ __launch_bounds__(256)
void softmax_ctx_kernel(const float* __restrict__ energy, const unsigned short* __restrict__ enc,
                        unsigned short* __restrict__ ctx_out /* Adec_cur + 1 */){
    __shared__ float wsm[Sn];
    __shared__ float red[256];
    int b = blockIdx.x, tid = threadIdx.x;
    float m = -1e30f;
    for (int s = tid; s < Sn; s += 256){ float e = energy[b*Sn + s]; wsm[s] = e; m = fmaxf(m, e); }
    red[tid] = m; __syncthreads();
    for (int o = 128; o; o >>= 1){ if (tid < o) red[tid] = fmaxf(red[tid], red[tid+o]); __syncthreads(); }
    m = red[0]; __syncthreads();
    float sum = 0.0f;
    for (int s = tid; s < Sn; s += 256){ float e = expf(wsm[s] - m); wsm[s] = e; sum += e; }
    red[tid] = sum; __syncthreads();
    for (int o = 128; o; o >>= 1){ if (tid < o) red[tid] += red[tid+o]; __syncthreads(); }
    float inv = 1.0f / red[0];
    float a0=0,a1=0,a2=0,a3=0;
    const uint2* base = (const uint2*)(enc + (size_t)b*Sn*Hn) + tid;  // 4 bf16 per thread per s
    #pragma unroll 4
    for (int s = 0; s < Sn; s++){
        float wv = wsm[s] * inv;
        uint2 v = base[(size_t)s*256];
        a0 += wv*bflo(v.x); a1 += wv*bfhi(v.x);
        a2 += wv*bflo(v.y); a3 += wv*bfhi(v.y);
    }
    unsigned short* cp = ctx_out + (size_t)b*KDEC + tid*4;
    cp[0] = f2bf(a0); cp[1] = f2bf(a1); cp[2] = f2bf(a2); cp[3] = f2bf(a3);
}

// ---------------- fc head + feedback ---------------------------------------
__global__ __launch_bounds__(256)
void fc_out_kernel(const unsigned short* __restrict__ h, const float* __restrict__ fcW,
                   const float* __restrict__ fcb, float* __restrict__ out,
                   unsigned short* __restrict__ prevy_slot /* Adec_next + 0 */, int d){
    __shared__ float red[256];
    int b = blockIdx.x, tid = threadIdx.x;
    uint2 v = ((const uint2*)(h + (size_t)b*Hn))[tid];
    float acc = fcW[tid*4+0]*bflo(v.x) + fcW[tid*4+1]*bfhi(v.x)
              + fcW[tid*4+2]*bflo(v.y) + fcW[tid*4+3]*bfhi(v.y);
    red[tid] = acc; __syncthreads();
    for (int o = 128; o; o >>= 1){ if (tid < o) red[tid] += red[tid+o]; __syncthreads(); }
    if (tid == 0){
        float p = red[0] + fcb[0];
        out[b*Tn + d] = p;
        prevy_slot[(size_t)b*KDEC] = f2bf(p);
    }
}

extern "C" void kernel_launch(void* const* d_in, const int* in_sizes, int n_in,
                              void* d_out, int out_size, void* d_ws, size_t ws_size,
                              hipStream_t stream){
    const float* src  = (const float*)d_in[0];
    const float* eWih = (const float*)d_in[1];
    const float* eWhh = (const float*)d_in[2];
    const float* ebih = (const float*)d_in[3];
    const float* ebhh = (const float*)d_in[4];
    const float* dWih = (const float*)d_in[5];
    const float* dWhh = (const float*)d_in[6];
    const float* dbih = (const float*)d_in[7];
    const float* dbhh = (const float*)d_in[8];
    const float* attnW= (const float*)d_in[9];
    const float* fcW  = (const float*)d_in[10];
    const float* fcb  = (const float*)d_in[11];
    float* out = (float*)d_out;

    char* base = (char*)d_ws;
    auto alloc = [&](size_t bytes){ void* p = base; base += (bytes + 255) & ~255ull; return p; };
    unsigned short* Wenc  = (unsigned short*)alloc((size_t)G4*KENC*2);
    float*          benc  = (float*)alloc(G4*4);
    unsigned short* Wdec  = (unsigned short*)alloc((size_t)G4*KDEC*2);
    float*          bdec  = (float*)alloc(G4*4);
    unsigned short* Wattn = (unsigned short*)alloc((size_t)Hn*Hn*2);
    unsigned short* srcbf = (unsigned short*)alloc((size_t)Bn*Sn*INd*2);
    unsigned short* enco  = (unsigned short*)alloc((size_t)Bn*Sn*Hn*2);
    unsigned short* hb0   = (unsigned short*)alloc((size_t)Bn*Hn*2);
    unsigned short* hb1   = (unsigned short*)alloc((size_t)Bn*Hn*2);
    float*          cbuf  = (float*)alloc((size_t)Bn*Hn*4);
    unsigned short* A0    = (unsigned short*)alloc((size_t)Bn*KDEC*2);
    unsigned short* A1    = (unsigned short*)alloc((size_t)Bn*KDEC*2);
    unsigned short* qbf   = (unsigned short*)alloc((size_t)Bn*Hn*2);
    float*          ener  = (float*)alloc((size_t)Bn*Sn*4);

    conv_src<<<4096, 256, 0, stream>>>(src, srcbf);
    pack_enc<<<4096, 256, 0, stream>>>(eWih, eWhh, ebih, ebhh, Wenc, benc);
    pack_dec<<<8192, 256, 0, stream>>>(dWih, dWhh, dbih, dbhh, Wdec, bdec);
    pack_attn<<<2048, 256, 0, stream>>>(attnW, Wattn);
    init_ws<<<1040, 256, 0, stream>>>(hb0, cbuf, A0, A1);

    unsigned short* hb[2] = {hb0, hb1};
    unsigned short* Ad[2] = {A0, A1};
    dim3 blk(256);
    dim3 gl(2, 64);
    dim3 gq(2, 16);

    for (int t = 0; t < Sn; t++){
        mfma_gemm<0, KENC><<<gl, blk, 0, stream>>>(hb[t&1], srcbf, Wenc, benc, cbuf,
                                                   hb[(t+1)&1], A0 + 1025, enco, t);
    }
    for (int d = 0; d < Tn; d++){
        unsigned short* hc = hb[d&1];
        unsigned short* hn = hb[(d+1)&1];
        unsigned short* Ac = Ad[d&1];
        unsigned short* An = Ad[(d+1)&1];
        mfma_gemm<2, KQ><<<gq, blk, 0, stream>>>(hc, nullptr, Wattn, nullptr, nullptr,
                                                 qbf, nullptr, nullptr, 0);
        energy_kernel<<<dim3(Bn, 84), blk, 0, stream>>>(qbf, enco, ener);
        softmax_ctx_kernel<<<Bn, blk, 0, stream>>>(ener, enco, Ac + 1);
        mfma_gemm<1, KDEC><<<gl, blk, 0, stream>>>(Ac, nullptr, Wdec, bdec, cbuf,
                                                   hn, An + 1025, nullptr, 0);
        fc_out_kernel<<<Bn, blk, 0, stream>>>(hn, fcW, fcb, out, An, d);
    }
}